// Round 9
// baseline (85.300 us; speedup 1.0000x reference)
//
#include <hip/hip_runtime.h>
#include <math.h>

#define MARGIN 1.9f
#define NMAX  640   // harness shape: n = 8*80 = 640 (kernel assumes n <= 640)
#define NSLOT 10    // NMAX / 64
#define ACH   4     // anchors per block (wave = anchor)
#define PCAP  192   // positive-list capacity (P ~ 64 for 10 random labels)

// ---------------------------------------------------------------------------
// K1: fused strip kernel. Block b owns anchors i0..i0+3 (160 blocks).
//  Per 64-col tile: stage cols into padded LDS (coalesced f4, stride 33 f4 —
//  measured 0 bank conflicts in R4-R6); wave wv computes 64 diff^2 dists for
//  its anchor (As4 read wave-uniform -> broadcast; one output per thread, no
//  cross-lane reduce); writes its dist row to LDS.
//  Then per-wave sweep (no syncs, no atomics): ballot-compacted positives,
//  10 INF-padded register negatives, 2-way split accumulator chains,
//  shuffle reduce, plain per-anchor partial stores.
// ---------------------------------------------------------------------------
__global__ __launch_bounds__(256) void fused_strip_kernel(
        const float* __restrict__ e, const int* __restrict__ lab,
        int n, int d,
        float* __restrict__ part_sum,          // [n]
        unsigned int* __restrict__ part_ne,    // [n]
        unsigned int* __restrict__ part_valid) // [n]
{
    __shared__ int    labs[NMAX];
    __shared__ float4 As4[ACH * 32];      // 4 anchors x 32 f4 (d<=128)
    __shared__ float4 Bs4[64 * 33];       // 64 cols x 32 f4, +1 f4 row pad
    __shared__ float  rows[ACH][NMAX];    // per-anchor dist row
    __shared__ float  pos[ACH][PCAP];

    const int tid  = threadIdx.x;
    const int lane = tid & 63;
    const int wv   = tid >> 6;
    const int i0   = blockIdx.x * ACH;
    const int nf4  = d >> 2;              // 32 for d=128

    for (int j = tid; j < n; j += 256) labs[j] = lab[j];
    const float4* eg = (const float4*)e;
    if (tid < ACH * nf4) {
        int a  = tid / nf4;
        int c4 = tid - a * nf4;
        int gi = i0 + a; if (gi >= n) gi = n - 1;
        As4[a * 32 + c4] = eg[(size_t)gi * nf4 + c4];
    }
    __syncthreads();

    // ---- dist rows, 64 columns per tile ----
    const int ntile = (n + 63) >> 6;      // 10
    for (int tt = 0; tt < ntile; ++tt) {
        const int col0 = tt << 6;
        // stage: 64 cols x nf4 f4, 8 per thread, coalesced
#pragma unroll
        for (int k = 0; k < 8; ++k) {
            int idx = tid + (k << 8);            // 0..2047
            int r = idx >> 5, c4 = idx & 31;     // col-in-tile, f4 index
            if (c4 < nf4) {
                int g = col0 + r; if (g >= n) g = n - 1;
                Bs4[r * 33 + c4] = eg[(size_t)g * nf4 + c4];
            }
        }
        __syncthreads();
        // dot: wave = anchor, lane = column
        const float4* bp = &Bs4[lane * 33];
        const float4* ap = &As4[wv * 32];
        float acc = 0.f;
#pragma unroll 8
        for (int t = 0; t < nf4; ++t) {
            float4 b = bp[t];
            float4 a = ap[t];                    // wave-uniform -> broadcast
            float dx;
            dx = a.x - b.x; acc = fmaf(dx, dx, acc);
            dx = a.y - b.y; acc = fmaf(dx, dx, acc);
            dx = a.z - b.z; acc = fmaf(dx, dx, acc);
            dx = a.w - b.w; acc = fmaf(dx, dx, acc);
        }
        int c = col0 + lane;
        if (c < n) rows[wv][c] = (acc == 0.f) ? 0.f : sqrtf(acc);
        __syncthreads();                         // protect Bs4 restage
    }

    // ---- per-wave sweep on anchor i = i0 + wv (wave-local LDS row) ----
    const int i = i0 + wv;
    const int my_lab = (i < n) ? labs[i] : -2147483647;
    const float INF = __builtin_huge_valf();

    float negv[NSLOT];
    int P = 0, nneg = 0;
#pragma unroll
    for (int s = 0; s < NSLOT; ++s) {
        int c = (s << 6) + lane;
        bool in = (i < n) && (c < n);
        float v = in ? rows[wv][c] : 0.f;
        int   l = in ? labs[c] : -2147483647;
        bool is_neg = in && (l != my_lab);
        negv[s] = is_neg ? v : INF;
        nneg += is_neg ? 1 : 0;
        bool is_pos = in && (l == my_lab) && (c != i);
        unsigned long long m = __ballot(is_pos);
        if (is_pos) {
            int off = __popcll(m & ((1ull << lane) - 1ull));
            int idx = P + off;
            if (idx < PCAP) pos[wv][idx] = v;
        }
        P += __popcll(m);
    }
    if (P > PCAP) P = PCAP;

    // split accumulator chains (slots 0-4 / 5-9) to break the dep chain
    float sum0 = 0.f, sum1 = 0.f;
    unsigned int c0 = 0, c1 = 0;
    for (int j = 0; j < P; ++j) {
        float a = pos[wv][j] + MARGIN;           // wave-uniform LDS broadcast
#pragma unroll
        for (int s = 0; s < 5; ++s) {
            float t = a - negv[s];
            if (t > 0.f) { sum0 += t; c0++; }
        }
#pragma unroll
        for (int s = 5; s < NSLOT; ++s) {
            float t = a - negv[s];
            if (t > 0.f) { sum1 += t; c1++; }
        }
    }
    float sum = sum0 + sum1;
    unsigned int cnt = c0 + c1;

    for (int off = 32; off > 0; off >>= 1) {
        sum  += __shfl_down(sum,  off, 64);
        cnt  += __shfl_down(cnt,  off, 64);
        nneg += __shfl_down(nneg, off, 64);
    }
    if (lane == 0 && i < n) {
        part_sum[i]   = sum;
        part_ne[i]    = cnt;
        part_valid[i] = (unsigned int)P * (unsigned int)nneg;
    }
}

// ---------------------------------------------------------------------------
// K2: reduce n partials -> out[4] = {loss, num_valid, num_non_easy, frac}
// ---------------------------------------------------------------------------
__global__ __launch_bounds__(256) void finalize_kernel(
        const float* __restrict__ part_sum,
        const unsigned int* __restrict__ part_ne,
        const unsigned int* __restrict__ part_valid,
        int nblk, float* __restrict__ out)
{
    __shared__ float red_s[4];
    __shared__ unsigned long long red_ne[4], red_nv[4];
    int tid = threadIdx.x;

    float s = 0.f;
    unsigned long long ne = 0, nv = 0;
    for (int b = tid; b < nblk; b += blockDim.x) {
        s  += part_sum[b];
        ne += part_ne[b];
        nv += part_valid[b];
    }
    for (int off = 32; off > 0; off >>= 1) {
        s  += __shfl_down(s,  off, 64);
        ne += __shfl_down(ne, off, 64);
        nv += __shfl_down(nv, off, 64);
    }
    int wave = tid >> 6;
    if ((tid & 63) == 0) { red_s[wave] = s; red_ne[wave] = ne; red_nv[wave] = nv; }
    __syncthreads();
    if (tid == 0) {
        float ts = 0.f; unsigned long long tne = 0, tnv = 0;
        int nwaves = (blockDim.x + 63) >> 6;
        for (int w = 0; w < nwaves; ++w) { ts += red_s[w]; tne += red_ne[w]; tnv += red_nv[w]; }
        float fne = (float)tne;
        float fnv = (float)tnv;
        out[0] = (fne > 0.f) ? (ts / fmaxf(fne, 1.f)) : 0.f;
        out[1] = fnv;
        out[2] = fne;
        out[3] = fne / (fnv + 1e-16f);
    }
}

extern "C" void kernel_launch(void* const* d_in, const int* in_sizes, int n_in,
                              void* d_out, int out_size, void* d_ws, size_t ws_size,
                              hipStream_t stream) {
    const float* e  = (const float*)d_in[0];
    const int* lab  = (const int*)d_in[1];
    int n = in_sizes[1];           // 640
    int d = in_sizes[0] / n;       // 128

    // ws layout: per-anchor partials (3 arrays of n); written before read
    char* ws = (char*)d_ws;
    float*        part_sum   = (float*)ws;
    unsigned int* part_ne    = (unsigned int*)(ws + (size_t)n * 4);
    unsigned int* part_valid = (unsigned int*)(ws + (size_t)n * 8);

    int blocks = (n + ACH - 1) / ACH;   // 160
    fused_strip_kernel<<<blocks, 256, 0, stream>>>(e, lab, n, d,
                                                   part_sum, part_ne, part_valid);
    finalize_kernel<<<1, 256, 0, stream>>>(part_sum, part_ne, part_valid,
                                           n, (float*)d_out);
}

// Round 10
// 77.421 us; speedup vs baseline: 1.1018x; 1.1018x over previous
//
#include <hip/hip_runtime.h>
#include <math.h>

#define MARGIN 1.9f
#define NMAX 1024   // max n supported by K2's LDS layout (n=640 here)

// ---------------------------------------------------------------------------
// K1: pairwise distance matrix via LDS-tiled "GEMM" on sum((a-b)^2).
// 64x32 tile per block (rows = anchors, cols), 256 threads = 16x16, each
// thread computes a 4x2 micro-tile -> 0.75 ds_read_b128 per output (vs 1.0
// at 2x2) and only 200 blocks (~1 per CU, no 2-deep tail like the 400-block
// 32x32 version measured at 8.8 us).
// LDS rows padded to 33 float4: A reads are quarter-wave-uniform
// (broadcast), B reads 2-way aliased (free per m136 measurement).
// ---------------------------------------------------------------------------
__global__ __launch_bounds__(256) void dist_kernel(
        const float* __restrict__ e, int n, int d,
        float* __restrict__ dist)
{
    __shared__ float4 As4[64 * 33];   // 64 rows x 32 f4 (+1 pad) = 33.8 KB
    __shared__ float4 Bs4[32 * 33];   // 32 cols x 32 f4 (+1 pad) = 16.9 KB
    const int tid  = threadIdx.x;
    const int row0 = blockIdx.y * 64;
    const int col0 = blockIdx.x * 32;
    const int nf4  = d >> 2;          // float4s per row (32 for d=128)

    const float4* eg = (const float4*)e;
    for (int f = tid; f < 64 * nf4; f += 256) {
        int r = f / nf4, c = f - r * nf4;
        int ga = row0 + r; if (ga >= n) ga = n - 1;   // clamp (n%64==0 here)
        As4[r * 33 + c] = eg[(size_t)ga * nf4 + c];
    }
    for (int f = tid; f < 32 * nf4; f += 256) {
        int r = f / nf4, c = f - r * nf4;
        int gb = col0 + r; if (gb >= n) gb = n - 1;
        Bs4[r * 33 + c] = eg[(size_t)gb * nf4 + c];
    }
    __syncthreads();

    const int tx = tid & 15, ty = tid >> 4;
    float a00 = 0.f, a01 = 0.f;
    float a10 = 0.f, a11 = 0.f;
    float a20 = 0.f, a21 = 0.f;
    float a30 = 0.f, a31 = 0.f;
    for (int t = 0; t < nf4; ++t) {
        float4 A0 = As4[(ty     ) * 33 + t];
        float4 A1 = As4[(ty + 16) * 33 + t];
        float4 A2 = As4[(ty + 32) * 33 + t];
        float4 A3 = As4[(ty + 48) * 33 + t];
        float4 B0 = Bs4[(tx     ) * 33 + t];
        float4 B1 = Bs4[(tx + 16) * 33 + t];
        float dx;
#define ACC(acc, A, B, comp) dx = A.comp - B.comp; acc = fmaf(dx, dx, acc)
#define ACC4(acc, A, B) ACC(acc, A, B, x); ACC(acc, A, B, y); ACC(acc, A, B, z); ACC(acc, A, B, w)
        ACC4(a00, A0, B0); ACC4(a01, A0, B1);
        ACC4(a10, A1, B0); ACC4(a11, A1, B1);
        ACC4(a20, A2, B0); ACC4(a21, A2, B1);
        ACC4(a30, A3, B0); ACC4(a31, A3, B1);
#undef ACC4
#undef ACC
    }

    const int r0 = row0 + ty, r1 = row0 + ty + 16;
    const int r2 = row0 + ty + 32, r3 = row0 + ty + 48;
    const int c0 = col0 + tx, c1 = col0 + tx + 16;
#define EMIT(rr, cc, acc) if ((rr) < n && (cc) < n) \
        dist[(size_t)(rr) * n + (cc)] = ((acc) == 0.f) ? 0.f : sqrtf(acc)
    EMIT(r0, c0, a00); EMIT(r0, c1, a01);
    EMIT(r1, c0, a10); EMIT(r1, c1, a11);
    EMIT(r2, c0, a20); EMIT(r2, c1, a21);
    EMIT(r3, c0, a30); EMIT(r3, c1, a31);
#undef EMIT
}

// ---------------------------------------------------------------------------
// K2: per-anchor triplet sweep (R6 verbatim — measured best). One block per
// anchor i. Plain stores of per-block partials to DISTINCT addresses — no
// atomics, no fences, no ticket. Visibility to K3 via inter-dispatch barrier.
// ---------------------------------------------------------------------------
__global__ __launch_bounds__(256) void triplet_kernel(
        const float* __restrict__ dist, const int* __restrict__ lab, int n,
        float* __restrict__ part_sum,          // [gridDim]
        unsigned int* __restrict__ part_ne,    // [gridDim]
        unsigned int* __restrict__ part_valid) // [gridDim]
{
    __shared__ float row[NMAX];
    __shared__ float pos[NMAX];
    __shared__ int   labs[NMAX];
    __shared__ int p_cnt, n_cnt;
    __shared__ float red_s[4];
    __shared__ unsigned int red_c[4];

    const int i    = blockIdx.x;
    const int tid  = threadIdx.x;
    const int lane = tid & 63;
    const int wv   = tid >> 6;

    if (tid == 0) { p_cnt = 0; n_cnt = 0; }
    for (int j = tid; j < n; j += 256) {
        row[j]  = dist[(size_t)i * n + j];
        labs[j] = lab[j];
    }
    __syncthreads();

    const int my_lab = labs[i];
    int local_neg = 0;
    for (int j = tid; j < n; j += 256) {
        if (labs[j] == my_lab) {
            if (j != i) { int k = atomicAdd(&p_cnt, 1); pos[k] = row[j]; }
        } else {
            local_neg++;
        }
    }
    for (int off = 32; off > 0; off >>= 1) local_neg += __shfl_down(local_neg, off, 64);
    if (lane == 0) atomicAdd(&n_cnt, local_neg);

    // negatives as INF-padded registers (NMAX/256 = 4 slots)
    const float INF = __builtin_huge_valf();
    int j0 = tid, j1 = tid + 256, j2 = tid + 512, j3 = tid + 768;
    float n0 = (j0 < n && labs[j0] != my_lab) ? row[j0] : INF;
    float n1 = (j1 < n && labs[j1] != my_lab) ? row[j1] : INF;
    float n2 = (j2 < n && labs[j2] != my_lab) ? row[j2] : INF;
    float n3 = (j3 < n && labs[j3] != my_lab) ? row[j3] : INF;
    __syncthreads();
    const int P = p_cnt, N = n_cnt;

    float sum = 0.f;
    unsigned int c = 0;
    for (int j = 0; j < P; ++j) {
        float a = pos[j] + MARGIN;        // LDS broadcast
        float t0 = a - n0; if (t0 > 0.f) { sum += t0; c++; }
        float t1 = a - n1; if (t1 > 0.f) { sum += t1; c++; }
        float t2 = a - n2; if (t2 > 0.f) { sum += t2; c++; }
        float t3 = a - n3; if (t3 > 0.f) { sum += t3; c++; }
    }

    for (int off = 32; off > 0; off >>= 1) {
        sum += __shfl_down(sum, off, 64);
        c   += __shfl_down(c,   off, 64);
    }
    if (lane == 0) { red_s[wv] = sum; red_c[wv] = c; }
    __syncthreads();

    if (tid == 0) {
        float s = 0.f; unsigned int cc = 0;
        for (int w = 0; w < 4; ++w) { s += red_s[w]; cc += red_c[w]; }
        part_sum[i]   = s;
        part_ne[i]    = cc;
        part_valid[i] = (unsigned int)P * (unsigned int)N;
    }
}

// ---------------------------------------------------------------------------
// K3: reduce 640 partials -> out[4] = {loss, num_valid, num_non_easy, frac}
// ---------------------------------------------------------------------------
__global__ __launch_bounds__(256) void finalize_kernel(
        const float* __restrict__ part_sum,
        const unsigned int* __restrict__ part_ne,
        const unsigned int* __restrict__ part_valid,
        int nblk, float* __restrict__ out)
{
    __shared__ float red_s[4];
    __shared__ unsigned long long red_ne[4], red_nv[4];
    int tid = threadIdx.x;

    float s = 0.f;
    unsigned long long ne = 0, nv = 0;
    for (int b = tid; b < nblk; b += blockDim.x) {
        s  += part_sum[b];
        ne += part_ne[b];
        nv += part_valid[b];
    }
    for (int off = 32; off > 0; off >>= 1) {
        s  += __shfl_down(s,  off, 64);
        ne += __shfl_down(ne, off, 64);
        nv += __shfl_down(nv, off, 64);
    }
    int wave = tid >> 6;
    if ((tid & 63) == 0) { red_s[wave] = s; red_ne[wave] = ne; red_nv[wave] = nv; }
    __syncthreads();
    if (tid == 0) {
        float ts = 0.f; unsigned long long tne = 0, tnv = 0;
        int nwaves = (blockDim.x + 63) >> 6;
        for (int w = 0; w < nwaves; ++w) { ts += red_s[w]; tne += red_ne[w]; tnv += red_nv[w]; }
        float fne = (float)tne;
        float fnv = (float)tnv;
        out[0] = (fne > 0.f) ? (ts / fmaxf(fne, 1.f)) : 0.f;
        out[1] = fnv;
        out[2] = fne;
        out[3] = fne / (fnv + 1e-16f);
    }
}

extern "C" void kernel_launch(void* const* d_in, const int* in_sizes, int n_in,
                              void* d_out, int out_size, void* d_ws, size_t ws_size,
                              hipStream_t stream) {
    const float* e  = (const float*)d_in[0];
    const int* lab  = (const int*)d_in[1];
    int n = in_sizes[1];           // 640
    int d = in_sizes[0] / n;       // 128

    // ws layout: [0..] per-block partials (3 arrays of n) | then dist (n*n)
    char* ws = (char*)d_ws;
    float*        part_sum   = (float*)ws;
    unsigned int* part_ne    = (unsigned int*)(ws + (size_t)n * 4);
    unsigned int* part_valid = (unsigned int*)(ws + (size_t)n * 8);
    size_t dist_off = ((size_t)n * 12 + 255) & ~(size_t)255;
    float*        dist       = (float*)(ws + dist_off);

    dim3 grid((n + 31) / 32, (n + 63) / 64);   // 20 x 10 = 200 blocks
    dist_kernel<<<grid, 256, 0, stream>>>(e, n, d, dist);
    triplet_kernel<<<n, 256, 0, stream>>>(dist, lab, n,
                                          part_sum, part_ne, part_valid);
    finalize_kernel<<<1, 256, 0, stream>>>(part_sum, part_ne, part_valid,
                                           n, (float*)d_out);
}

// Round 11
// 73.990 us; speedup vs baseline: 1.1529x; 1.0464x over previous
//
#include <hip/hip_runtime.h>
#include <math.h>

#define MARGIN 1.9f
#define TILE 32
#define NMAX 1024   // max n supported by K2's LDS layout (n=640 here)
#define SEGCAP 256  // per-wave positive-segment capacity (P_total ~63 here)

// ---------------------------------------------------------------------------
// K1: pairwise distance matrix via LDS-tiled "GEMM" on sum((a-b)^2).
// R6-measured version, byte-identical: 32x32 tile, 2x2 micro-tile, 400
// blocks. Measured: ~8.8 us, SQ_LDS_BANK_CONFLICT = 0. (64x32/4x2 variant
// measured WORSE in R10 — bigger LDS halves co-residency.)
// ---------------------------------------------------------------------------
__global__ __launch_bounds__(256) void dist_kernel(
        const float* __restrict__ e, int n, int d,
        float* __restrict__ dist)
{
    __shared__ float As[TILE * 132];
    __shared__ float Bs[TILE * 132];
    const int tid  = threadIdx.x;
    const int row0 = blockIdx.y * TILE;
    const int col0 = blockIdx.x * TILE;
    const int nf4  = d >> 2;                    // float4s per row (32)

    const float4* eg  = (const float4*)e;
    float4* As4 = (float4*)As;
    float4* Bs4 = (float4*)Bs;
    for (int f = tid; f < TILE * nf4; f += 256) {
        int r = f / nf4, c = f - r * nf4;
        int ga = row0 + r; if (ga >= n) ga = n - 1;   // clamp (n%32==0 here)
        int gb = col0 + r; if (gb >= n) gb = n - 1;
        As4[r * 33 + c] = eg[(size_t)ga * nf4 + c];
        Bs4[r * 33 + c] = eg[(size_t)gb * nf4 + c];
    }
    __syncthreads();

    const int tx = tid & 15, ty = tid >> 4;
    float a00 = 0.f, a01 = 0.f, a10 = 0.f, a11 = 0.f;
    for (int t = 0; t < nf4; ++t) {
        float4 A0 = As4[ty * 33 + t];
        float4 A1 = As4[(ty + 16) * 33 + t];
        float4 B0 = Bs4[tx * 33 + t];
        float4 B1 = Bs4[(tx + 16) * 33 + t];
        float dx;
#define ACC(acc, A, B, comp) dx = A.comp - B.comp; acc = fmaf(dx, dx, acc)
        ACC(a00, A0, B0, x); ACC(a00, A0, B0, y); ACC(a00, A0, B0, z); ACC(a00, A0, B0, w);
        ACC(a01, A0, B1, x); ACC(a01, A0, B1, y); ACC(a01, A0, B1, z); ACC(a01, A0, B1, w);
        ACC(a10, A1, B0, x); ACC(a10, A1, B0, y); ACC(a10, A1, B0, z); ACC(a10, A1, B0, w);
        ACC(a11, A1, B1, x); ACC(a11, A1, B1, y); ACC(a11, A1, B1, z); ACC(a11, A1, B1, w);
#undef ACC
    }

    const int r0 = row0 + ty, r1 = row0 + ty + 16;
    const int c0 = col0 + tx, c1 = col0 + tx + 16;
#define EMIT(rr, cc, acc) if ((rr) < n && (cc) < n) \
        dist[(size_t)(rr) * n + (cc)] = ((acc) == 0.f) ? 0.f : sqrtf(acc)
    EMIT(r0, c0, a00); EMIT(r0, c1, a01);
    EMIT(r1, c0, a10); EMIT(r1, c1, a11);
#undef EMIT
}

// ---------------------------------------------------------------------------
// K2: per-anchor triplet sweep. One block per anchor i. Changes vs R6:
//  - row/labels staged with float4/int4 (1 coalesced round instead of 3)
//  - positive compaction via per-wave ballot+popcount into 4 LDS segments
//    (zero LDS atomics; R6's ~63 same-address atomicAdds serialized ~2-3K
//    cycles per block)
//  - negative count dropped: N = n - P - 1 identically
// Sweep / reduction / plain distinct-address partial stores unchanged.
// ---------------------------------------------------------------------------
__global__ __launch_bounds__(256) void triplet_kernel(
        const float* __restrict__ dist, const int* __restrict__ lab, int n,
        float* __restrict__ part_sum,          // [gridDim]
        unsigned int* __restrict__ part_ne,    // [gridDim]
        unsigned int* __restrict__ part_valid) // [gridDim]
{
    __shared__ float row[NMAX];
    __shared__ int   labs[NMAX];
    __shared__ float pos[4][SEGCAP];
    __shared__ int   cnt[4];
    __shared__ float red_s[4];
    __shared__ unsigned int red_c[4];

    const int i    = blockIdx.x;
    const int tid  = threadIdx.x;
    const int lane = tid & 63;
    const int wv   = tid >> 6;

    // vectorized staging (n % 4 == 0; n/4 <= 256 for n <= 1024)
    {
        const float4* r4 = (const float4*)(dist + (size_t)i * n);
        const int4*   l4 = (const int4*)lab;
        const int nf = n >> 2;
        for (int t = tid; t < nf; t += 256) {
            ((float4*)row)[t]  = r4[t];
            ((int4*)labs)[t]   = l4[t];
        }
    }
    __syncthreads();

    const int my_lab = labs[i];

    // per-wave ballot compaction: wave w owns 64-col tiles t = w, w+4, ...
    int my_cnt = 0;
    const int ntile = (n + 63) >> 6;          // 10
    for (int t = wv; t < ntile; t += 4) {
        int c = (t << 6) + lane;
        bool in = (c < n);
        float v = in ? row[c] : 0.f;
        bool is_pos = in && (labs[c] == my_lab) && (c != i);
        unsigned long long m = __ballot(is_pos);
        if (is_pos) {
            int off = __popcll(m & ((1ull << lane) - 1ull));
            int idx = my_cnt + off;
            if (idx < SEGCAP) pos[wv][idx] = v;
        }
        my_cnt += __popcll(m);
    }
    if (my_cnt > SEGCAP) my_cnt = SEGCAP;
    if (lane == 0) cnt[wv] = my_cnt;

    // negatives as INF-padded registers (NMAX/256 = 4 slots); row/labs are
    // stable after the first barrier, safe to read here
    const float INF = __builtin_huge_valf();
    int j0 = tid, j1 = tid + 256, j2 = tid + 512, j3 = tid + 768;
    float n0 = (j0 < n && labs[j0] != my_lab) ? row[j0] : INF;
    float n1 = (j1 < n && labs[j1] != my_lab) ? row[j1] : INF;
    float n2 = (j2 < n && labs[j2] != my_lab) ? row[j2] : INF;
    float n3 = (j3 < n && labs[j3] != my_lab) ? row[j3] : INF;
    __syncthreads();   // cnt[] and pos[][] visible

    const int P = cnt[0] + cnt[1] + cnt[2] + cnt[3];
    const int N = n - P - 1;   // exactly: #neg = n - #same_label, same = P+1

    float sum = 0.f;
    unsigned int c = 0;
    for (int w = 0; w < 4; ++w) {
        const int kw = cnt[w];
        for (int j = 0; j < kw; ++j) {
            float a = pos[w][j] + MARGIN;     // wave-uniform LDS broadcast
            float t0 = a - n0; if (t0 > 0.f) { sum += t0; c++; }
            float t1 = a - n1; if (t1 > 0.f) { sum += t1; c++; }
            float t2 = a - n2; if (t2 > 0.f) { sum += t2; c++; }
            float t3 = a - n3; if (t3 > 0.f) { sum += t3; c++; }
        }
    }

    for (int off = 32; off > 0; off >>= 1) {
        sum += __shfl_down(sum, off, 64);
        c   += __shfl_down(c,   off, 64);
    }
    if (lane == 0) { red_s[wv] = sum; red_c[wv] = c; }
    __syncthreads();

    if (tid == 0) {
        float s = 0.f; unsigned int cc = 0;
        for (int w = 0; w < 4; ++w) { s += red_s[w]; cc += red_c[w]; }
        part_sum[i]   = s;
        part_ne[i]    = cc;
        part_valid[i] = (unsigned int)P * (unsigned int)N;
    }
}

// ---------------------------------------------------------------------------
// K3: reduce 640 partials -> out[4] = {loss, num_valid, num_non_easy, frac}
// ---------------------------------------------------------------------------
__global__ __launch_bounds__(256) void finalize_kernel(
        const float* __restrict__ part_sum,
        const unsigned int* __restrict__ part_ne,
        const unsigned int* __restrict__ part_valid,
        int nblk, float* __restrict__ out)
{
    __shared__ float red_s[4];
    __shared__ unsigned long long red_ne[4], red_nv[4];
    int tid = threadIdx.x;

    float s = 0.f;
    unsigned long long ne = 0, nv = 0;
    for (int b = tid; b < nblk; b += blockDim.x) {
        s  += part_sum[b];
        ne += part_ne[b];
        nv += part_valid[b];
    }
    for (int off = 32; off > 0; off >>= 1) {
        s  += __shfl_down(s,  off, 64);
        ne += __shfl_down(ne, off, 64);
        nv += __shfl_down(nv, off, 64);
    }
    int wave = tid >> 6;
    if ((tid & 63) == 0) { red_s[wave] = s; red_ne[wave] = ne; red_nv[wave] = nv; }
    __syncthreads();
    if (tid == 0) {
        float ts = 0.f; unsigned long long tne = 0, tnv = 0;
        int nwaves = (blockDim.x + 63) >> 6;
        for (int w = 0; w < nwaves; ++w) { ts += red_s[w]; tne += red_ne[w]; tnv += red_nv[w]; }
        float fne = (float)tne;
        float fnv = (float)tnv;
        out[0] = (fne > 0.f) ? (ts / fmaxf(fne, 1.f)) : 0.f;
        out[1] = fnv;
        out[2] = fne;
        out[3] = fne / (fnv + 1e-16f);
    }
}

extern "C" void kernel_launch(void* const* d_in, const int* in_sizes, int n_in,
                              void* d_out, int out_size, void* d_ws, size_t ws_size,
                              hipStream_t stream) {
    const float* e  = (const float*)d_in[0];
    const int* lab  = (const int*)d_in[1];
    int n = in_sizes[1];           // 640
    int d = in_sizes[0] / n;       // 128

    // ws layout: [0..] per-block partials (3 arrays of n) | then dist (n*n)
    char* ws = (char*)d_ws;
    float*        part_sum   = (float*)ws;
    unsigned int* part_ne    = (unsigned int*)(ws + (size_t)n * 4);
    unsigned int* part_valid = (unsigned int*)(ws + (size_t)n * 8);
    size_t dist_off = ((size_t)n * 12 + 255) & ~(size_t)255;
    float*        dist       = (float*)(ws + dist_off);

    int nt = (n + TILE - 1) / TILE;   // 20
    dim3 grid(nt, nt);
    dist_kernel<<<grid, 256, 0, stream>>>(e, n, d, dist);
    triplet_kernel<<<n, 256, 0, stream>>>(dist, lab, n,
                                          part_sum, part_ne, part_valid);
    finalize_kernel<<<1, 256, 0, stream>>>(part_sum, part_ne, part_valid,
                                           n, (float*)d_out);
}